// Round 9
// baseline (328.479 us; speedup 1.0000x reference)
//
#include <hip/hip_runtime.h>
#include <hip/hip_bf16.h>

#define N_CTX 4096
#define NH    16
#define DH    64
#define DIM   1024   // NH * DH
#define NSPLIT 4
#define KT_PER_SPLIT (N_CTX / 64 / NSPLIT)   // 16

typedef __attribute__((ext_vector_type(8))) short bf16x8;  // 8 bf16 in 4 VGPRs
typedef __attribute__((ext_vector_type(4))) float f32x4;   // MFMA C/D

// RNE float->bf16
__device__ __forceinline__ ushort f2bf(float f) {
    union { float f; unsigned u; } x; x.f = f;
    unsigned r = (x.u + 0x7FFFu + ((x.u >> 16) & 1u)) >> 16;
    return (ushort)r;
}
__device__ __forceinline__ float bf2f(ushort u) {
    union { unsigned u; float f; } x; x.u = ((unsigned)u) << 16; return x.f;
}
__device__ __forceinline__ unsigned fbits(float f) {
    union { float f; unsigned u; } x; x.f = f; return x.u;
}
// pack two floats to packed bf16 pair (round-half-up), 3 VALU ops
__device__ __forceinline__ unsigned pack_bf16(float lo, float hi) {
    unsigned a = fbits(lo) + 0x8000u;
    unsigned b = fbits(hi) + 0x8000u;
#if defined(__has_builtin)
#if __has_builtin(__builtin_amdgcn_perm)
    return __builtin_amdgcn_perm(b, a, 0x07060302u);
#else
    return (a >> 16) | (b & 0xFFFF0000u);
#endif
#else
    return (a >> 16) | (b & 0xFFFF0000u);
#endif
}
__device__ __forceinline__ float fast_exp2(float x) {
#if defined(__has_builtin)
#if __has_builtin(__builtin_amdgcn_exp2f)
    return __builtin_amdgcn_exp2f(x);
#else
    return exp2f(x);
#endif
#else
    return exp2f(x);
#endif
}

// 0.125 * log2(e): folded into Q during prep; softmax shift-invariance lets us
// drop the bias term entirely (p = exp2(s) directly, p <= 2^18.1).
#define SC 0.18033688011112042f

// ---------------------------------------------------------------------------
// prep: x (N, DIM) fp32 -> rope -> l2norm -> * qk_scale -> * premul
//       -> xb bf16 [h][n][d]
// ---------------------------------------------------------------------------
__global__ __launch_bounds__(256) void prep_kernel(
    const float* __restrict__ x, const float* __restrict__ qk_scale,
    ushort* __restrict__ xb, float premul)
{
    const int lane = threadIdx.x & 63;
    const int wave = threadIdx.x >> 6;
    const int row  = blockIdx.x * 4 + wave;   // row = n*NH + h
    const int n = row >> 4;
    const int h = row & 15;

    float val = x[(size_t)n * DIM + h * DH + lane];
    float other = __shfl_xor(val, 1, 64);

    const int i = lane >> 1;
    float inv_freq = 1.0f / powf(10000.0f, (float)i * (1.0f / 32.0f));
    float ang = (float)n * inv_freq;
    float s, c;
    sincosf(ang, &s, &c);

    float r = (lane & 1) ? fmaf(other, s, val * c)
                         : fmaf(val, c, -(other * s));

    float ss = r * r;
    #pragma unroll
    for (int off = 32; off > 0; off >>= 1)
        ss += __shfl_xor(ss, off, 64);
    float invn = 1.0f / fmaxf(sqrtf(ss), 1e-12f);
    float scl  = qk_scale[lane] * premul;

    xb[((size_t)h * N_CTX + n) * DH + lane] = f2bf(r * invn * scl);
}

// ---------------------------------------------------------------------------
// vtrans: v (N, DIM) fp32 -> vt bf16 [h][d][n]
// ---------------------------------------------------------------------------
__global__ __launch_bounds__(256) void vtrans_kernel(
    const float* __restrict__ v, ushort* __restrict__ vt)
{
    __shared__ ushort L[64][68];
    const int kt = blockIdx.x, h = blockIdx.y, t = threadIdx.x;

    for (int e = t; e < 4096; e += 256) {
        int key = e >> 6, d = e & 63;
        float f = v[(size_t)(kt * 64 + key) * DIM + h * DH + d];
        L[d][key] = f2bf(f);
    }
    __syncthreads();
    for (int e = t; e < 4096; e += 256) {
        int d = e >> 6, key = e & 63;
        vt[((size_t)h * DH + d) * N_CTX + kt * 64 + key] = L[d][key];
    }
}

// ---------------------------------------------------------------------------
// wconv: w_out (DIM, DIM) fp32 -> bf16 row-major
// ---------------------------------------------------------------------------
__global__ __launch_bounds__(256) void wconv_kernel(
    const float* __restrict__ w, ushort* __restrict__ wb)
{
    int i = (blockIdx.x * 256 + threadIdx.x) * 4;
    float4 f = *(const float4*)&w[i];
    ushort4 u;
    u.x = f2bf(f.x); u.y = f2bf(f.y); u.z = f2bf(f.z); u.w = f2bf(f.w);
    *(ushort4*)&wb[i] = u;
}

// ---------------------------------------------------------------------------
// attn: MFMA flash attention, softmax scale folded into Q, split-K x4.
// Block: 128 queries x head x split(1024 keys), 256 threads (4 waves).
// Wave w owns queries w*32..+32 end-to-end.
// K-fragments loaded DIRECTLY from global (L2-resident, coalesced 128B rows)
// -> no Ks LDS. V staged in LDS (barrier pair). P: half-size two-phase LDS
// buffer [128][40] (same-wave in-order DS makes the ks=0->ks=1 WAR safe).
// LDS = 9.2 + 10.2 = 19.5 KB -> 8 blocks/CU capacity; grid 2048 fills it.
// Outputs bf16 O-partials (pre-division) + fp32 l-partials.
// ---------------------------------------------------------------------------
__global__ __launch_bounds__(256) void attn_kernel(
    const ushort* __restrict__ qb, const ushort* __restrict__ kb,
    const ushort* __restrict__ vt, ushort* __restrict__ opart,
    float* __restrict__ lpart)
{
    __shared__ ushort Vt[64][72];    // [d][key]
    __shared__ ushort Ps[128][40];   // [query][key-local 0..31], two-phase

    const int h     = blockIdx.y;
    const int qbase = blockIdx.x * 128;
    const int sp    = blockIdx.z;
    const int kbase = sp * (N_CTX / NSPLIT);
    const int t    = threadIdx.x;
    const int w    = t >> 6;
    const int lane = t & 63;
    const int l15  = lane & 15;
    const int quad = lane >> 4;

    // Q B-fragments: 2 query-tiles x 2 k-halves (queries w*32 + qt*16 + l15)
    bf16x8 qf[2][2];
    #pragma unroll
    for (int qt = 0; qt < 2; qt++) {
        const size_t qrow = ((size_t)h * N_CTX + qbase + w * 32 + qt * 16 + l15) * DH;
        qf[qt][0] = *(const bf16x8*)&qb[qrow + quad * 8];
        qf[qt][1] = *(const bf16x8*)&qb[qrow + 32 + quad * 8];
    }

    float l_part[2] = {0.0f, 0.0f};
    f32x4 o_acc[4][2];
    #pragma unroll
    for (int dt = 0; dt < 4; dt++)
        #pragma unroll
        for (int qt = 0; qt < 2; qt++)
            o_acc[dt][qt] = (f32x4){0.f, 0.f, 0.f, 0.f};

    // V staging: 256 threads, rows sr and sr+32, 16B chunk sc
    const int sr = t >> 3;
    const int sc = (t & 7) * 8;
    const ushort* vp0 = &vt[((size_t)h * DH + sr) * N_CTX + kbase + sc];
    const ushort* vp1 = vp0 + (size_t)32 * N_CTX;
    bf16x8 vr0 = *(const bf16x8*)vp0;
    bf16x8 vr1 = *(const bf16x8*)vp1;

    // K fragment base: row (kbase + kt*64 + j*16 + l15), col quad*8
    const ushort* kfp = &kb[((size_t)h * N_CTX + kbase + l15) * DH + quad * 8];

    for (int kt = 0; kt < KT_PER_SPLIT; kt++) {
        __syncthreads();                       // A: all waves done with prev Vt
        *(bf16x8*)&Vt[sr][sc]      = vr0;
        *(bf16x8*)&Vt[sr + 32][sc] = vr1;
        __syncthreads();                       // B: staging visible
        if (kt + 1 < KT_PER_SPLIT) {           // prefetch next V tile into regs
            vr0 = *(const bf16x8*)(vp0 + (size_t)(kt + 1) * 64);
            vr1 = *(const bf16x8*)(vp1 + (size_t)(kt + 1) * 64);
        }

        #pragma unroll
        for (int ks = 0; ks < 2; ks++) {
            // ---- S phase for 32 keys (subtiles jj=0,1), both query-tiles
            #pragma unroll
            for (int jj = 0; jj < 2; jj++) {
                const int j = ks * 2 + jj;
                const ushort* kr = kfp + (size_t)(kt * 64 + j * 16) * DH;
                bf16x8 kf0 = *(const bf16x8*)kr;
                bf16x8 kf1 = *(const bf16x8*)(kr + 32);

                #pragma unroll
                for (int qt = 0; qt < 2; qt++) {
                    f32x4 s = (f32x4){0.f, 0.f, 0.f, 0.f};
                    s = __builtin_amdgcn_mfma_f32_16x16x32_bf16(kf0, qf[qt][0], s, 0, 0, 0);
                    s = __builtin_amdgcn_mfma_f32_16x16x32_bf16(kf1, qf[qt][1], s, 0, 0, 0);

                    float p0 = fast_exp2(s.x), p1 = fast_exp2(s.y);
                    float p2 = fast_exp2(s.z), p3 = fast_exp2(s.w);
                    l_part[qt] += (p0 + p1) + (p2 + p3);
                    uint2 pk;
                    pk.x = pack_bf16(p0, p1);
                    pk.y = pack_bf16(p2, p3);
                    *(uint2*)&Ps[w * 32 + qt * 16 + l15][jj * 16 + quad * 4] = pk;
                }
            }

            // ---- PV phase for these 32 keys (vf shared across query-tiles)
            bf16x8 pf0 = *(const bf16x8*)&Ps[w * 32 + l15][quad * 8];
            bf16x8 pf1 = *(const bf16x8*)&Ps[w * 32 + 16 + l15][quad * 8];
            #pragma unroll
            for (int dt = 0; dt < 4; dt++) {
                bf16x8 vf = *(const bf16x8*)&Vt[dt * 16 + l15][ks * 32 + quad * 8];
                o_acc[dt][0] = __builtin_amdgcn_mfma_f32_16x16x32_bf16(vf, pf0, o_acc[dt][0], 0, 0, 0);
                o_acc[dt][1] = __builtin_amdgcn_mfma_f32_16x16x32_bf16(vf, pf1, o_acc[dt][1], 0, 0, 0);
            }
        }
    }

    // l: reduce across quads (disjoint key subsets per quad)
    #pragma unroll
    for (int qt = 0; qt < 2; qt++) {
        float v = l_part[qt];
        v += __shfl_xor(v, 16, 64);
        v += __shfl_xor(v, 32, 64);
        if (quad == 0)
            lpart[(size_t)sp * NH * N_CTX + (size_t)h * N_CTX
                  + qbase + w * 32 + qt * 16 + l15] = v;
    }

    // O partial (pre-division), bf16 [sp][N][DIM]
    #pragma unroll
    for (int qt = 0; qt < 2; qt++)
        #pragma unroll
        for (int dt = 0; dt < 4; dt++) {
            f32x4 o = o_acc[dt][qt];
            ushort4 ov;
            ov.x = f2bf(o.x); ov.y = f2bf(o.y);
            ov.z = f2bf(o.z); ov.w = f2bf(o.w);
            *(ushort4*)&opart[((size_t)sp * N_CTX + qbase + w * 32 + qt * 16 + l15) * DIM
                              + h * DH + dt * 16 + quad * 4] = ov;
        }
}

// ---------------------------------------------------------------------------
// combine: attnb[n][c] = bf16( sum_sp O_sp[n][c] / sum_sp l_sp[n,h] )
// ---------------------------------------------------------------------------
__global__ __launch_bounds__(256) void combine_kernel(
    const ushort* __restrict__ opart, const float* __restrict__ lpart,
    ushort* __restrict__ attnb)
{
    const int idx = blockIdx.x * 256 + threadIdx.x;   // one per 4 elements
    const int n   = idx >> 8;
    const int rem = idx & 255;
    const int h   = rem >> 4;
    const size_t e = (size_t)n * DIM + h * DH + (rem & 15) * 4;

    float s0 = 0.f, s1 = 0.f, s2 = 0.f, s3 = 0.f, lsum = 0.f;
    #pragma unroll
    for (int sp = 0; sp < NSPLIT; sp++) {
        ushort4 u = *(const ushort4*)&opart[(size_t)sp * N_CTX * DIM + e];
        s0 += bf2f(u.x); s1 += bf2f(u.y); s2 += bf2f(u.z); s3 += bf2f(u.w);
        lsum += lpart[(size_t)sp * NH * N_CTX + (size_t)h * N_CTX + n];
    }
    float li = 1.0f / lsum;

    ushort4 r;
    r.x = f2bf(s0 * li); r.y = f2bf(s1 * li);
    r.z = f2bf(s2 * li); r.w = f2bf(s3 * li);
    *(ushort4*)&attnb[e] = r;
}

// ---------------------------------------------------------------------------
// proj (MFMA): out[n][o] = sum_c A[n][c] * W[o][c] + b[o]   (unchanged)
// ---------------------------------------------------------------------------
__global__ __launch_bounds__(256) void proj_kernel(
    const ushort* __restrict__ A, const ushort* __restrict__ W,
    const float* __restrict__ bias, float* __restrict__ out)
{
    __shared__ ushort As[128][72];
    __shared__ ushort Ws[64][72];

    const int nbase = blockIdx.x * 128;
    const int obase = blockIdx.y * 64;
    const int t    = threadIdx.x;
    const int w    = t >> 6;
    const int lane = t & 63;
    const int l15  = lane & 15;
    const int quad = lane >> 4;
    const int rw   = (w >> 1) * 64;
    const int cw   = (w & 1) * 32;

    f32x4 acc[4][2];
    #pragma unroll
    for (int mt = 0; mt < 4; mt++)
        #pragma unroll
        for (int nt = 0; nt < 2; nt++)
            acc[mt][nt] = (f32x4){0.f, 0.f, 0.f, 0.f};

    for (int kt = 0; kt < DIM / 64; kt++) {
        const int kb = kt * 64;
        __syncthreads();
        #pragma unroll
        for (int i = 0; i < 4; i++) {
            int c = t + i * 256, r = c >> 3, c8 = c & 7;
            *(bf16x8*)&As[r][c8 * 8] =
                *(const bf16x8*)&A[(size_t)(nbase + r) * DIM + kb + c8 * 8];
        }
        #pragma unroll
        for (int i = 0; i < 2; i++) {
            int c = t + i * 256, r = c >> 3, c8 = c & 7;
            *(bf16x8*)&Ws[r][c8 * 8] =
                *(const bf16x8*)&W[(size_t)(obase + r) * DIM + kb + c8 * 8];
        }
        __syncthreads();

        bf16x8 af[4][2], bfr[2][2];
        #pragma unroll
        for (int mt = 0; mt < 4; mt++)
            #pragma unroll
            for (int kh = 0; kh < 2; kh++)
                af[mt][kh] = *(const bf16x8*)&As[rw + mt * 16 + l15][kh * 32 + quad * 8];
        #pragma unroll
        for (int nt = 0; nt < 2; nt++)
            #pragma unroll
            for (int kh = 0; kh < 2; kh++)
                bfr[nt][kh] = *(const bf16x8*)&Ws[cw + nt * 16 + l15][kh * 32 + quad * 8];

        #pragma unroll
        for (int mt = 0; mt < 4; mt++)
            #pragma unroll
            for (int nt = 0; nt < 2; nt++) {
                acc[mt][nt] = __builtin_amdgcn_mfma_f32_16x16x32_bf16(af[mt][0], bfr[nt][0], acc[mt][nt], 0, 0, 0);
                acc[mt][nt] = __builtin_amdgcn_mfma_f32_16x16x32_bf16(af[mt][1], bfr[nt][1], acc[mt][nt], 0, 0, 0);
            }
    }

    #pragma unroll
    for (int nt = 0; nt < 2; nt++) {
        int o = obase + cw + nt * 16 + l15;
        float bb = bias[o];
        #pragma unroll
        for (int mt = 0; mt < 4; mt++) {
            int nrow = nbase + rw + mt * 16 + quad * 4;
            out[(size_t)(nrow + 0) * DIM + o] = acc[mt][nt].x + bb;
            out[(size_t)(nrow + 1) * DIM + o] = acc[mt][nt].y + bb;
            out[(size_t)(nrow + 2) * DIM + o] = acc[mt][nt].z + bb;
            out[(size_t)(nrow + 3) * DIM + o] = acc[mt][nt].w + bb;
        }
    }
}

// ---------------------------------------------------------------------------
extern "C" void kernel_launch(void* const* d_in, const int* in_sizes, int n_in,
                              void* d_out, int out_size, void* d_ws, size_t ws_size,
                              hipStream_t stream)
{
    const float* q        = (const float*)d_in[0];
    const float* k        = (const float*)d_in[1];
    const float* v        = (const float*)d_in[2];
    const float* qk_scale = (const float*)d_in[3];
    const float* w_out    = (const float*)d_in[4];
    const float* b_out    = (const float*)d_in[5];
    float* out = (float*)d_out;

    const size_t per = (size_t)NH * N_CTX * DH;      // 4.19M elements
    ushort* qb    = (ushort*)d_ws;
    ushort* kb    = qb + per;
    ushort* vtg   = kb + per;
    ushort* attnb = vtg + per;                       // (N, DIM) bf16
    ushort* wb    = attnb + per;                     // (DIM, DIM) bf16
    ushort* opart = wb + (size_t)DIM * DIM;          // NSPLIT x (N, DIM) bf16
    float*  lpart = (float*)(opart + (size_t)NSPLIT * N_CTX * DIM);

    prep_kernel<<<dim3(N_CTX * NH / 4), 256, 0, stream>>>(q, qk_scale, qb, SC);
    prep_kernel<<<dim3(N_CTX * NH / 4), 256, 0, stream>>>(k, qk_scale, kb, 1.0f);
    vtrans_kernel<<<dim3(N_CTX / 64, NH), 256, 0, stream>>>(v, vtg);
    wconv_kernel<<<dim3(DIM * DIM / 1024), 256, 0, stream>>>(w_out, wb);
    attn_kernel<<<dim3(N_CTX / 128, NH, NSPLIT), 256, 0, stream>>>(qb, kb, vtg, opart, lpart);
    combine_kernel<<<dim3(N_CTX * DIM / 4 / 256), 256, 0, stream>>>(opart, lpart, attnb);
    proj_kernel<<<dim3(N_CTX / 128, DIM / 64), 256, 0, stream>>>(attnb, wb, b_out, out);
}

// Round 10
// 266.341 us; speedup vs baseline: 1.2333x; 1.2333x over previous
//
#include <hip/hip_runtime.h>
#include <hip/hip_bf16.h>

#define N_CTX 4096
#define NH    16
#define DH    64
#define DIM   1024   // NH * DH
#define NSPLIT 2
#define KT_PER_SPLIT (N_CTX / 64 / NSPLIT)   // 32

typedef __attribute__((ext_vector_type(8))) short bf16x8;  // 8 bf16 in 4 VGPRs
typedef __attribute__((ext_vector_type(4))) float f32x4;   // MFMA C/D

// RNE float->bf16 (non-hot paths)
__device__ __forceinline__ ushort f2bf(float f) {
    union { float f; unsigned u; } x; x.f = f;
    unsigned r = (x.u + 0x7FFFu + ((x.u >> 16) & 1u)) >> 16;
    return (ushort)r;
}
__device__ __forceinline__ unsigned fbits(float f) {
    union { float f; unsigned u; } x; x.f = f; return x.u;
}
// pack two floats to packed bf16 pair (round-half-up), 3 VALU ops
__device__ __forceinline__ unsigned pack_bf16(float lo, float hi) {
    unsigned a = fbits(lo) + 0x8000u;
    unsigned b = fbits(hi) + 0x8000u;
#if defined(__has_builtin)
#if __has_builtin(__builtin_amdgcn_perm)
    return __builtin_amdgcn_perm(b, a, 0x07060302u);
#else
    return (a >> 16) | (b & 0xFFFF0000u);
#endif
#else
    return (a >> 16) | (b & 0xFFFF0000u);
#endif
}
__device__ __forceinline__ float fast_exp2(float x) {
#if defined(__has_builtin)
#if __has_builtin(__builtin_amdgcn_exp2f)
    return __builtin_amdgcn_exp2f(x);
#else
    return exp2f(x);
#endif
#else
    return exp2f(x);
#endif
}

// 0.125 * log2(e): folded into Q during prep; softmax shift-invariance lets us
// drop the bias term entirely (p = exp2(s) directly, p <= 2^18.1).
#define SC 0.18033688011112042f

// ---------------------------------------------------------------------------
// prep: x (N, DIM) fp32 -> rope -> l2norm -> * qk_scale -> * premul
//       -> xb bf16 [h][n][d]
// ---------------------------------------------------------------------------
__global__ __launch_bounds__(256) void prep_kernel(
    const float* __restrict__ x, const float* __restrict__ qk_scale,
    ushort* __restrict__ xb, float premul)
{
    const int lane = threadIdx.x & 63;
    const int wave = threadIdx.x >> 6;
    const int row  = blockIdx.x * 4 + wave;   // row = n*NH + h
    const int n = row >> 4;
    const int h = row & 15;

    float val = x[(size_t)n * DIM + h * DH + lane];
    float other = __shfl_xor(val, 1, 64);

    const int i = lane >> 1;
    float inv_freq = 1.0f / powf(10000.0f, (float)i * (1.0f / 32.0f));
    float ang = (float)n * inv_freq;
    float s, c;
    sincosf(ang, &s, &c);

    float r = (lane & 1) ? fmaf(other, s, val * c)
                         : fmaf(val, c, -(other * s));

    float ss = r * r;
    #pragma unroll
    for (int off = 32; off > 0; off >>= 1)
        ss += __shfl_xor(ss, off, 64);
    float invn = 1.0f / fmaxf(sqrtf(ss), 1e-12f);
    float scl  = qk_scale[lane] * premul;

    xb[((size_t)h * N_CTX + n) * DH + lane] = f2bf(r * invn * scl);
}

// ---------------------------------------------------------------------------
// vtrans: v (N, DIM) fp32 -> vt bf16 [h][d][n]
// ---------------------------------------------------------------------------
__global__ __launch_bounds__(256) void vtrans_kernel(
    const float* __restrict__ v, ushort* __restrict__ vt)
{
    __shared__ ushort L[64][68];
    const int kt = blockIdx.x, h = blockIdx.y, t = threadIdx.x;

    for (int e = t; e < 4096; e += 256) {
        int key = e >> 6, d = e & 63;
        float f = v[(size_t)(kt * 64 + key) * DIM + h * DH + d];
        L[d][key] = f2bf(f);
    }
    __syncthreads();
    for (int e = t; e < 4096; e += 256) {
        int d = e >> 6, key = e & 63;
        vt[((size_t)h * DH + d) * N_CTX + kt * 64 + key] = L[d][key];
    }
}

// ---------------------------------------------------------------------------
// wconv: w_out (DIM, DIM) fp32 -> bf16 row-major
// ---------------------------------------------------------------------------
__global__ __launch_bounds__(256) void wconv_kernel(
    const float* __restrict__ w, ushort* __restrict__ wb)
{
    int i = (blockIdx.x * 256 + threadIdx.x) * 4;
    float4 f = *(const float4*)&w[i];
    ushort4 u;
    u.x = f2bf(f.x); u.y = f2bf(f.y); u.z = f2bf(f.z); u.w = f2bf(f.w);
    *(ushort4*)&wb[i] = u;
}

// ---------------------------------------------------------------------------
// attn: MFMA flash attention (round-8 proven structure).
// Block: 128 queries x head x split, 256 threads (4 waves).
// Wave w owns queries w*32..+32 end-to-end; K/V frags reused across the
// wave's 2 query-tiles. 2 barriers/ktile; register prefetch of next tile.
// ---------------------------------------------------------------------------
__global__ __launch_bounds__(256) void attn_kernel(
    const ushort* __restrict__ qb, const ushort* __restrict__ kb,
    const ushort* __restrict__ vt, float* __restrict__ opart,
    float* __restrict__ lpart)
{
    __shared__ ushort Ks[64][72];    // [key][d]
    __shared__ ushort Vt[64][72];    // [d][key]
    __shared__ ushort Ps[128][72];   // [query][key]

    const int h     = blockIdx.y;
    const int qbase = blockIdx.x * 128;
    const int sp    = blockIdx.z;
    const int kbase = sp * (N_CTX / NSPLIT);
    const int t    = threadIdx.x;
    const int w    = t >> 6;
    const int lane = t & 63;
    const int l15  = lane & 15;
    const int quad = lane >> 4;

    // Q B-fragments: 2 query-tiles x 2 k-halves (queries w*32 + qt*16 + l15)
    bf16x8 qf[2][2];
    #pragma unroll
    for (int qt = 0; qt < 2; qt++) {
        const size_t qrow = ((size_t)h * N_CTX + qbase + w * 32 + qt * 16 + l15) * DH;
        qf[qt][0] = *(const bf16x8*)&qb[qrow + quad * 8];
        qf[qt][1] = *(const bf16x8*)&qb[qrow + 32 + quad * 8];
    }

    float l_part[2] = {0.0f, 0.0f};
    f32x4 o_acc[4][2];
    #pragma unroll
    for (int dt = 0; dt < 4; dt++)
        #pragma unroll
        for (int qt = 0; qt < 2; qt++)
            o_acc[dt][qt] = (f32x4){0.f, 0.f, 0.f, 0.f};

    // staging: 256 threads, 2 x 16B chunks each of K and V (rows sr, sr+32)
    const int sr = t >> 3;
    const int sc = (t & 7) * 8;
    const ushort* kp0 = &kb[((size_t)h * N_CTX + kbase + sr) * DH + sc];
    const ushort* kp1 = kp0 + (size_t)32 * DH;
    const ushort* vp0 = &vt[((size_t)h * DH + sr) * N_CTX + kbase + sc];
    const ushort* vp1 = vp0 + (size_t)32 * N_CTX;
    bf16x8 kr0 = *(const bf16x8*)kp0, kr1 = *(const bf16x8*)kp1;
    bf16x8 vr0 = *(const bf16x8*)vp0, vr1 = *(const bf16x8*)vp1;

    for (int kt = 0; kt < KT_PER_SPLIT; kt++) {
        __syncthreads();                       // A: all waves done with prev tile
        *(bf16x8*)&Ks[sr][sc]      = kr0;
        *(bf16x8*)&Ks[sr + 32][sc] = kr1;
        *(bf16x8*)&Vt[sr][sc]      = vr0;
        *(bf16x8*)&Vt[sr + 32][sc] = vr1;
        __syncthreads();                       // B: staging visible
        if (kt + 1 < KT_PER_SPLIT) {           // prefetch next tile into regs
            kr0 = *(const bf16x8*)(kp0 + (size_t)(kt + 1) * 64 * DH);
            kr1 = *(const bf16x8*)(kp1 + (size_t)(kt + 1) * 64 * DH);
            vr0 = *(const bf16x8*)(vp0 + (size_t)(kt + 1) * 64);
            vr1 = *(const bf16x8*)(vp1 + (size_t)(kt + 1) * 64);
        }

        // ---- S phase: 4 key-subtiles; kf frags shared across 2 query-tiles
        #pragma unroll
        for (int j = 0; j < 4; j++) {
            bf16x8 kf0 = *(const bf16x8*)&Ks[j * 16 + l15][quad * 8];
            bf16x8 kf1 = *(const bf16x8*)&Ks[j * 16 + l15][32 + quad * 8];
            f32x4 s0 = (f32x4){0.f, 0.f, 0.f, 0.f};
            f32x4 s1 = (f32x4){0.f, 0.f, 0.f, 0.f};
            s0 = __builtin_amdgcn_mfma_f32_16x16x32_bf16(kf0, qf[0][0], s0, 0, 0, 0);
            s1 = __builtin_amdgcn_mfma_f32_16x16x32_bf16(kf0, qf[1][0], s1, 0, 0, 0);
            s0 = __builtin_amdgcn_mfma_f32_16x16x32_bf16(kf1, qf[0][1], s0, 0, 0, 0);
            s1 = __builtin_amdgcn_mfma_f32_16x16x32_bf16(kf1, qf[1][1], s1, 0, 0, 0);

            // p = exp2(s) (scale pre-folded into Q; bias dropped by shift-inv.)
            {
                float p0 = fast_exp2(s0.x), p1 = fast_exp2(s0.y);
                float p2 = fast_exp2(s0.z), p3 = fast_exp2(s0.w);
                l_part[0] += (p0 + p1) + (p2 + p3);
                uint2 pk; pk.x = pack_bf16(p0, p1); pk.y = pack_bf16(p2, p3);
                *(uint2*)&Ps[w * 32 + l15][j * 16 + quad * 4] = pk;
            }
            {
                float p0 = fast_exp2(s1.x), p1 = fast_exp2(s1.y);
                float p2 = fast_exp2(s1.z), p3 = fast_exp2(s1.w);
                l_part[1] += (p0 + p1) + (p2 + p3);
                uint2 pk; pk.x = pack_bf16(p0, p1); pk.y = pack_bf16(p2, p3);
                *(uint2*)&Ps[w * 32 + 16 + l15][j * 16 + quad * 4] = pk;
            }
        }

        // ---- PV phase: vf frags shared across the wave's 2 query-tiles
        #pragma unroll
        for (int ks = 0; ks < 2; ks++) {
            bf16x8 pf0 = *(const bf16x8*)&Ps[w * 32 + l15][ks * 32 + quad * 8];
            bf16x8 pf1 = *(const bf16x8*)&Ps[w * 32 + 16 + l15][ks * 32 + quad * 8];
            #pragma unroll
            for (int dt = 0; dt < 4; dt++) {
                bf16x8 vf = *(const bf16x8*)&Vt[dt * 16 + l15][ks * 32 + quad * 8];
                o_acc[dt][0] = __builtin_amdgcn_mfma_f32_16x16x32_bf16(vf, pf0, o_acc[dt][0], 0, 0, 0);
                o_acc[dt][1] = __builtin_amdgcn_mfma_f32_16x16x32_bf16(vf, pf1, o_acc[dt][1], 0, 0, 0);
            }
        }
    }

    // l: reduce across quads (disjoint key subsets per quad)
    #pragma unroll
    for (int qt = 0; qt < 2; qt++) {
        float v = l_part[qt];
        v += __shfl_xor(v, 16, 64);
        v += __shfl_xor(v, 32, 64);
        if (quad == 0)
            lpart[(size_t)sp * NH * N_CTX + (size_t)h * N_CTX
                  + qbase + w * 32 + qt * 16 + l15] = v;
    }

    // O partial (pre-division), fp32 (N, DIM) layout per split
    #pragma unroll
    for (int qt = 0; qt < 2; qt++)
        #pragma unroll
        for (int dt = 0; dt < 4; dt++) {
            f32x4 o = o_acc[dt][qt];
            float4 ov; ov.x = o.x; ov.y = o.y; ov.z = o.z; ov.w = o.w;
            *(float4*)&opart[((size_t)sp * N_CTX + qbase + w * 32 + qt * 16 + l15) * DIM
                             + h * DH + dt * 16 + quad * 4] = ov;
        }
}

// ---------------------------------------------------------------------------
// combine: attnb[n][c] = bf16( (O0+O1)[n][c] / (l0+l1)[n,h] )
// ---------------------------------------------------------------------------
__global__ __launch_bounds__(256) void combine_kernel(
    const float* __restrict__ opart, const float* __restrict__ lpart,
    ushort* __restrict__ attnb)
{
    const int idx = blockIdx.x * 256 + threadIdx.x;   // one per 4 elements
    const int n   = idx >> 8;
    const int rem = idx & 255;
    const int h   = rem >> 4;
    const size_t e = (size_t)n * DIM + h * DH + (rem & 15) * 4;

    float4 o0 = *(const float4*)&opart[e];
    float4 o1 = *(const float4*)&opart[(size_t)N_CTX * DIM + e];
    float l0 = lpart[(size_t)h * N_CTX + n];
    float l1 = lpart[(size_t)NH * N_CTX + (size_t)h * N_CTX + n];
    float li = 1.0f / (l0 + l1);

    ushort4 r;
    r.x = f2bf((o0.x + o1.x) * li);
    r.y = f2bf((o0.y + o1.y) * li);
    r.z = f2bf((o0.z + o1.z) * li);
    r.w = f2bf((o0.w + o1.w) * li);
    *(ushort4*)&attnb[e] = r;
}

// ---------------------------------------------------------------------------
// proj (MFMA): out[n][o] = sum_c A[n][c] * W[o][c] + b[o]
// RETILED: 64x64 block tile, grid (64,16) = 1024 blocks = 4/CU (was 512=2/CU,
// the hidden ~70-90us bottleneck). 4 waves in 2x2, each 32x32 (2x2 MFMA tiles).
// LDS 18.4 KB.
// ---------------------------------------------------------------------------
__global__ __launch_bounds__(256) void proj_kernel(
    const ushort* __restrict__ A, const ushort* __restrict__ W,
    const float* __restrict__ bias, float* __restrict__ out)
{
    __shared__ ushort As[64][72];
    __shared__ ushort Ws[64][72];

    const int nbase = blockIdx.x * 64;
    const int obase = blockIdx.y * 64;
    const int t    = threadIdx.x;
    const int w    = t >> 6;
    const int lane = t & 63;
    const int l15  = lane & 15;
    const int quad = lane >> 4;
    const int rw   = (w >> 1) * 32;   // wave row base in tile
    const int cw   = (w & 1) * 32;    // wave col base in tile

    f32x4 acc[2][2];
    #pragma unroll
    for (int mt = 0; mt < 2; mt++)
        #pragma unroll
        for (int nt = 0; nt < 2; nt++)
            acc[mt][nt] = (f32x4){0.f, 0.f, 0.f, 0.f};

    for (int kt = 0; kt < DIM / 64; kt++) {
        const int kb = kt * 64;
        __syncthreads();
        #pragma unroll
        for (int i = 0; i < 2; i++) {           // A tile: 64 rows x 64 k
            int c = t + i * 256, r = c >> 3, c8 = c & 7;
            *(bf16x8*)&As[r][c8 * 8] =
                *(const bf16x8*)&A[(size_t)(nbase + r) * DIM + kb + c8 * 8];
        }
        #pragma unroll
        for (int i = 0; i < 2; i++) {           // W tile: 64 rows x 64 k
            int c = t + i * 256, r = c >> 3, c8 = c & 7;
            *(bf16x8*)&Ws[r][c8 * 8] =
                *(const bf16x8*)&W[(size_t)(obase + r) * DIM + kb + c8 * 8];
        }
        __syncthreads();

        bf16x8 af[2][2], bfr[2][2];
        #pragma unroll
        for (int mt = 0; mt < 2; mt++)
            #pragma unroll
            for (int kh = 0; kh < 2; kh++)
                af[mt][kh] = *(const bf16x8*)&As[rw + mt * 16 + l15][kh * 32 + quad * 8];
        #pragma unroll
        for (int nt = 0; nt < 2; nt++)
            #pragma unroll
            for (int kh = 0; kh < 2; kh++)
                bfr[nt][kh] = *(const bf16x8*)&Ws[cw + nt * 16 + l15][kh * 32 + quad * 8];

        #pragma unroll
        for (int mt = 0; mt < 2; mt++)
            #pragma unroll
            for (int nt = 0; nt < 2; nt++) {
                acc[mt][nt] = __builtin_amdgcn_mfma_f32_16x16x32_bf16(af[mt][0], bfr[nt][0], acc[mt][nt], 0, 0, 0);
                acc[mt][nt] = __builtin_amdgcn_mfma_f32_16x16x32_bf16(af[mt][1], bfr[nt][1], acc[mt][nt], 0, 0, 0);
            }
    }

    // epilogue: C layout col(l15)=o, row(quad*4+r)=n
    #pragma unroll
    for (int nt = 0; nt < 2; nt++) {
        int o = obase + cw + nt * 16 + l15;
        float bb = bias[o];
        #pragma unroll
        for (int mt = 0; mt < 2; mt++) {
            int nrow = nbase + rw + mt * 16 + quad * 4;
            out[(size_t)(nrow + 0) * DIM + o] = acc[mt][nt].x + bb;
            out[(size_t)(nrow + 1) * DIM + o] = acc[mt][nt].y + bb;
            out[(size_t)(nrow + 2) * DIM + o] = acc[mt][nt].z + bb;
            out[(size_t)(nrow + 3) * DIM + o] = acc[mt][nt].w + bb;
        }
    }
}

// ---------------------------------------------------------------------------
extern "C" void kernel_launch(void* const* d_in, const int* in_sizes, int n_in,
                              void* d_out, int out_size, void* d_ws, size_t ws_size,
                              hipStream_t stream)
{
    const float* q        = (const float*)d_in[0];
    const float* k        = (const float*)d_in[1];
    const float* v        = (const float*)d_in[2];
    const float* qk_scale = (const float*)d_in[3];
    const float* w_out    = (const float*)d_in[4];
    const float* b_out    = (const float*)d_in[5];
    float* out = (float*)d_out;

    const size_t per = (size_t)NH * N_CTX * DH;      // 4.19M elements
    ushort* qb    = (ushort*)d_ws;
    ushort* kb    = qb + per;
    ushort* vtg   = kb + per;
    ushort* attnb = vtg + per;                       // (N, DIM) bf16
    ushort* wb    = attnb + per;                     // (DIM, DIM) bf16
    float*  opart = (float*)(wb + (size_t)DIM * DIM);        // 2 x (N, DIM) fp32
    float*  lpart = opart + (size_t)NSPLIT * N_CTX * DIM;    // 2 x NH x N fp32

    prep_kernel<<<dim3(N_CTX * NH / 4), 256, 0, stream>>>(q, qk_scale, qb, SC);
    prep_kernel<<<dim3(N_CTX * NH / 4), 256, 0, stream>>>(k, qk_scale, kb, 1.0f);
    vtrans_kernel<<<dim3(N_CTX / 64, NH), 256, 0, stream>>>(v, vtg);
    wconv_kernel<<<dim3(DIM * DIM / 1024), 256, 0, stream>>>(w_out, wb);
    attn_kernel<<<dim3(N_CTX / 128, NH, NSPLIT), 256, 0, stream>>>(qb, kb, vtg, opart, lpart);
    combine_kernel<<<dim3(N_CTX * DIM / 4 / 256), 256, 0, stream>>>(opart, lpart, attnb);
    proj_kernel<<<dim3(N_CTX / 64, DIM / 64), 256, 0, stream>>>(attnb, wb, b_out, out);
}

// Round 11
// 232.903 us; speedup vs baseline: 1.4104x; 1.1436x over previous
//
#include <hip/hip_runtime.h>
#include <hip/hip_bf16.h>

#define N_CTX 4096
#define NH    16
#define DH    64
#define DIM   1024   // NH * DH
#define NSPLIT 2
#define KT_PER_SPLIT (N_CTX / 64 / NSPLIT)   // 32

typedef __attribute__((ext_vector_type(8))) short bf16x8;  // 8 bf16 in 4 VGPRs
typedef __attribute__((ext_vector_type(4))) float f32x4;   // MFMA C/D

// RNE float->bf16 (non-hot paths)
__device__ __forceinline__ ushort f2bf(float f) {
    union { float f; unsigned u; } x; x.f = f;
    unsigned r = (x.u + 0x7FFFu + ((x.u >> 16) & 1u)) >> 16;
    return (ushort)r;
}
__device__ __forceinline__ float bf2f(ushort u) {
    union { unsigned u; float f; } x; x.u = ((unsigned)u) << 16; return x.f;
}
__device__ __forceinline__ unsigned fbits(float f) {
    union { float f; unsigned u; } x; x.f = f; return x.u;
}
// pack two floats to packed bf16 pair (round-half-up), 3 VALU ops
__device__ __forceinline__ unsigned pack_bf16(float lo, float hi) {
    unsigned a = fbits(lo) + 0x8000u;
    unsigned b = fbits(hi) + 0x8000u;
#if defined(__has_builtin)
#if __has_builtin(__builtin_amdgcn_perm)
    return __builtin_amdgcn_perm(b, a, 0x07060302u);
#else
    return (a >> 16) | (b & 0xFFFF0000u);
#endif
#else
    return (a >> 16) | (b & 0xFFFF0000u);
#endif
}
__device__ __forceinline__ float fast_exp2(float x) {
#if defined(__has_builtin)
#if __has_builtin(__builtin_amdgcn_exp2f)
    return __builtin_amdgcn_exp2f(x);
#else
    return exp2f(x);
#endif
#else
    return exp2f(x);
#endif
}
// hw sin/cos of x (radians): revolutions + v_fract + v_sin/v_cos.
// arg-rounding error ~5e-4 rad at |x|~4096 — negligible vs bf16 quantization.
__device__ __forceinline__ void fast_sincos(float ang, float* s, float* c) {
#if defined(__has_builtin)
#if __has_builtin(__builtin_amdgcn_sinf) && __has_builtin(__builtin_amdgcn_cosf) && __has_builtin(__builtin_amdgcn_fractf)
    float rev = __builtin_amdgcn_fractf(ang * 0.15915494309189535f);
    *s = __builtin_amdgcn_sinf(rev);
    *c = __builtin_amdgcn_cosf(rev);
    return;
#endif
#endif
    sincosf(ang, s, c);
}

// 0.125 * log2(e): folded into Q during prep; softmax shift-invariance lets us
// drop the bias term entirely (p = exp2(s) directly, p <= 2^18.1).
#define SC 0.18033688011112042f
// log2(10000)/32
#define LF 0.4152410118609203f

// ---------------------------------------------------------------------------
// prep (fused q+k): x (N, DIM) fp32 -> rope -> l2norm -> * qk_scale * premul
//       -> xb bf16 [h][n][d].  blockIdx.y: 0 = q (premul SC), 1 = k.
// Fast-math: exp2 for inv_freq, HW sin/cos, rsqrt.
// ---------------------------------------------------------------------------
__global__ __launch_bounds__(256) void prep_kernel(
    const float* __restrict__ qg, const float* __restrict__ kg,
    const float* __restrict__ qk_scale,
    ushort* __restrict__ qb, ushort* __restrict__ kb)
{
    const int lane = threadIdx.x & 63;
    const int wave = threadIdx.x >> 6;
    const int row  = blockIdx.x * 4 + wave;   // row = n*NH + h
    const int n = row >> 4;
    const int h = row & 15;
    const int isk = blockIdx.y;
    const float* __restrict__ x = isk ? kg : qg;
    ushort* __restrict__ xb = isk ? kb : qb;
    const float premul = isk ? 1.0f : SC;

    float val = x[(size_t)n * DIM + h * DH + lane];
    float other = __shfl_xor(val, 1, 64);

    const int i = lane >> 1;
    float inv_freq = fast_exp2((float)i * -LF);   // 10000^(-i/32)
    float ang = (float)n * inv_freq;
    float s, c;
    fast_sincos(ang, &s, &c);

    float r = (lane & 1) ? fmaf(other, s, val * c)
                         : fmaf(val, c, -(other * s));

    float ss = r * r;
    #pragma unroll
    for (int off = 32; off > 0; off >>= 1)
        ss += __shfl_xor(ss, off, 64);
    float invn = rsqrtf(fmaxf(ss, 1e-24f));
    float scl  = qk_scale[lane] * premul;

    xb[((size_t)h * N_CTX + n) * DH + lane] = f2bf(r * invn * scl);
}

// ---------------------------------------------------------------------------
// vtrans: v (N, DIM) fp32 -> vt bf16 [h][d][n]
// ---------------------------------------------------------------------------
__global__ __launch_bounds__(256) void vtrans_kernel(
    const float* __restrict__ v, ushort* __restrict__ vt)
{
    __shared__ ushort L[64][68];
    const int kt = blockIdx.x, h = blockIdx.y, t = threadIdx.x;

    for (int e = t; e < 4096; e += 256) {
        int key = e >> 6, d = e & 63;
        float f = v[(size_t)(kt * 64 + key) * DIM + h * DH + d];
        L[d][key] = f2bf(f);
    }
    __syncthreads();
    for (int e = t; e < 4096; e += 256) {
        int d = e >> 6, key = e & 63;
        vt[((size_t)h * DH + d) * N_CTX + kt * 64 + key] = L[d][key];
    }
}

// ---------------------------------------------------------------------------
// wconv: w_out (DIM, DIM) fp32 -> bf16 row-major
// ---------------------------------------------------------------------------
__global__ __launch_bounds__(256) void wconv_kernel(
    const float* __restrict__ w, ushort* __restrict__ wb)
{
    int i = (blockIdx.x * 256 + threadIdx.x) * 4;
    float4 f = *(const float4*)&w[i];
    ushort4 u;
    u.x = f2bf(f.x); u.y = f2bf(f.y); u.z = f2bf(f.z); u.w = f2bf(f.w);
    *(ushort4*)&wb[i] = u;
}

// ---------------------------------------------------------------------------
// attn: MFMA flash attention (round-8/10 proven structure), bf16 O-partials.
// Block: 128 queries x head x split, 256 threads (4 waves).
// ---------------------------------------------------------------------------
__global__ __launch_bounds__(256) void attn_kernel(
    const ushort* __restrict__ qb, const ushort* __restrict__ kb,
    const ushort* __restrict__ vt, ushort* __restrict__ opart,
    float* __restrict__ lpart)
{
    __shared__ ushort Ks[64][72];    // [key][d]
    __shared__ ushort Vt[64][72];    // [d][key]
    __shared__ ushort Ps[128][72];   // [query][key]

    const int h     = blockIdx.y;
    const int qbase = blockIdx.x * 128;
    const int sp    = blockIdx.z;
    const int kbase = sp * (N_CTX / NSPLIT);
    const int t    = threadIdx.x;
    const int w    = t >> 6;
    const int lane = t & 63;
    const int l15  = lane & 15;
    const int quad = lane >> 4;

    // Q B-fragments: 2 query-tiles x 2 k-halves (queries w*32 + qt*16 + l15)
    bf16x8 qf[2][2];
    #pragma unroll
    for (int qt = 0; qt < 2; qt++) {
        const size_t qrow = ((size_t)h * N_CTX + qbase + w * 32 + qt * 16 + l15) * DH;
        qf[qt][0] = *(const bf16x8*)&qb[qrow + quad * 8];
        qf[qt][1] = *(const bf16x8*)&qb[qrow + 32 + quad * 8];
    }

    float l_part[2] = {0.0f, 0.0f};
    f32x4 o_acc[4][2];
    #pragma unroll
    for (int dt = 0; dt < 4; dt++)
        #pragma unroll
        for (int qt = 0; qt < 2; qt++)
            o_acc[dt][qt] = (f32x4){0.f, 0.f, 0.f, 0.f};

    // staging: 256 threads, 2 x 16B chunks each of K and V (rows sr, sr+32)
    const int sr = t >> 3;
    const int sc = (t & 7) * 8;
    const ushort* kp0 = &kb[((size_t)h * N_CTX + kbase + sr) * DH + sc];
    const ushort* kp1 = kp0 + (size_t)32 * DH;
    const ushort* vp0 = &vt[((size_t)h * DH + sr) * N_CTX + kbase + sc];
    const ushort* vp1 = vp0 + (size_t)32 * N_CTX;
    bf16x8 kr0 = *(const bf16x8*)kp0, kr1 = *(const bf16x8*)kp1;
    bf16x8 vr0 = *(const bf16x8*)vp0, vr1 = *(const bf16x8*)vp1;

    for (int kt = 0; kt < KT_PER_SPLIT; kt++) {
        __syncthreads();                       // A: all waves done with prev tile
        *(bf16x8*)&Ks[sr][sc]      = kr0;
        *(bf16x8*)&Ks[sr + 32][sc] = kr1;
        *(bf16x8*)&Vt[sr][sc]      = vr0;
        *(bf16x8*)&Vt[sr + 32][sc] = vr1;
        __syncthreads();                       // B: staging visible
        if (kt + 1 < KT_PER_SPLIT) {           // prefetch next tile into regs
            kr0 = *(const bf16x8*)(kp0 + (size_t)(kt + 1) * 64 * DH);
            kr1 = *(const bf16x8*)(kp1 + (size_t)(kt + 1) * 64 * DH);
            vr0 = *(const bf16x8*)(vp0 + (size_t)(kt + 1) * 64);
            vr1 = *(const bf16x8*)(vp1 + (size_t)(kt + 1) * 64);
        }

        // ---- S phase: 4 key-subtiles; kf frags shared across 2 query-tiles
        #pragma unroll
        for (int j = 0; j < 4; j++) {
            bf16x8 kf0 = *(const bf16x8*)&Ks[j * 16 + l15][quad * 8];
            bf16x8 kf1 = *(const bf16x8*)&Ks[j * 16 + l15][32 + quad * 8];
            f32x4 s0 = (f32x4){0.f, 0.f, 0.f, 0.f};
            f32x4 s1 = (f32x4){0.f, 0.f, 0.f, 0.f};
            s0 = __builtin_amdgcn_mfma_f32_16x16x32_bf16(kf0, qf[0][0], s0, 0, 0, 0);
            s1 = __builtin_amdgcn_mfma_f32_16x16x32_bf16(kf0, qf[1][0], s1, 0, 0, 0);
            s0 = __builtin_amdgcn_mfma_f32_16x16x32_bf16(kf1, qf[0][1], s0, 0, 0, 0);
            s1 = __builtin_amdgcn_mfma_f32_16x16x32_bf16(kf1, qf[1][1], s1, 0, 0, 0);

            {
                float p0 = fast_exp2(s0.x), p1 = fast_exp2(s0.y);
                float p2 = fast_exp2(s0.z), p3 = fast_exp2(s0.w);
                l_part[0] += (p0 + p1) + (p2 + p3);
                uint2 pk; pk.x = pack_bf16(p0, p1); pk.y = pack_bf16(p2, p3);
                *(uint2*)&Ps[w * 32 + l15][j * 16 + quad * 4] = pk;
            }
            {
                float p0 = fast_exp2(s1.x), p1 = fast_exp2(s1.y);
                float p2 = fast_exp2(s1.z), p3 = fast_exp2(s1.w);
                l_part[1] += (p0 + p1) + (p2 + p3);
                uint2 pk; pk.x = pack_bf16(p0, p1); pk.y = pack_bf16(p2, p3);
                *(uint2*)&Ps[w * 32 + 16 + l15][j * 16 + quad * 4] = pk;
            }
        }

        // ---- PV phase: vf frags shared across the wave's 2 query-tiles
        #pragma unroll
        for (int ks = 0; ks < 2; ks++) {
            bf16x8 pf0 = *(const bf16x8*)&Ps[w * 32 + l15][ks * 32 + quad * 8];
            bf16x8 pf1 = *(const bf16x8*)&Ps[w * 32 + 16 + l15][ks * 32 + quad * 8];
            #pragma unroll
            for (int dt = 0; dt < 4; dt++) {
                bf16x8 vf = *(const bf16x8*)&Vt[dt * 16 + l15][ks * 32 + quad * 8];
                o_acc[dt][0] = __builtin_amdgcn_mfma_f32_16x16x32_bf16(vf, pf0, o_acc[dt][0], 0, 0, 0);
                o_acc[dt][1] = __builtin_amdgcn_mfma_f32_16x16x32_bf16(vf, pf1, o_acc[dt][1], 0, 0, 0);
            }
        }
    }

    // l: reduce across quads (disjoint key subsets per quad)
    #pragma unroll
    for (int qt = 0; qt < 2; qt++) {
        float v = l_part[qt];
        v += __shfl_xor(v, 16, 64);
        v += __shfl_xor(v, 32, 64);
        if (quad == 0)
            lpart[(size_t)sp * NH * N_CTX + (size_t)h * N_CTX
                  + qbase + w * 32 + qt * 16 + l15] = v;
    }

    // O partial (pre-division), bf16 [sp][N][DIM]
    #pragma unroll
    for (int qt = 0; qt < 2; qt++)
        #pragma unroll
        for (int dt = 0; dt < 4; dt++) {
            f32x4 o = o_acc[dt][qt];
            ushort4 ov;
            ov.x = f2bf(o.x); ov.y = f2bf(o.y);
            ov.z = f2bf(o.z); ov.w = f2bf(o.w);
            *(ushort4*)&opart[((size_t)sp * N_CTX + qbase + w * 32 + qt * 16 + l15) * DIM
                              + h * DH + dt * 16 + quad * 4] = ov;
        }
}

// ---------------------------------------------------------------------------
// combine: attnb[n][c] = bf16( (O0+O1)[n][c] / (l0+l1)[n,h] )
// ---------------------------------------------------------------------------
__global__ __launch_bounds__(256) void combine_kernel(
    const ushort* __restrict__ opart, const float* __restrict__ lpart,
    ushort* __restrict__ attnb)
{
    const int idx = blockIdx.x * 256 + threadIdx.x;   // one per 4 elements
    const int n   = idx >> 8;
    const int rem = idx & 255;
    const int h   = rem >> 4;
    const size_t e = (size_t)n * DIM + h * DH + (rem & 15) * 4;

    float s0 = 0.f, s1 = 0.f, s2 = 0.f, s3 = 0.f, lsum = 0.f;
    #pragma unroll
    for (int sp = 0; sp < NSPLIT; sp++) {
        ushort4 u = *(const ushort4*)&opart[(size_t)sp * N_CTX * DIM + e];
        s0 += bf2f(u.x); s1 += bf2f(u.y); s2 += bf2f(u.z); s3 += bf2f(u.w);
        lsum += lpart[(size_t)sp * NH * N_CTX + (size_t)h * N_CTX + n];
    }
    float li = 1.0f / lsum;

    ushort4 r;
    r.x = f2bf(s0 * li); r.y = f2bf(s1 * li);
    r.z = f2bf(s2 * li); r.w = f2bf(s3 * li);
    *(ushort4*)&attnb[e] = r;
}

// ---------------------------------------------------------------------------
// proj (MFMA): out[n][o] = sum_c A[n][c] * W[o][c] + b[o]
// 64x64 block tile, grid (64,16) = 1024 blocks = 4/CU. (round-10 structure)
// ---------------------------------------------------------------------------
__global__ __launch_bounds__(256) void proj_kernel(
    const ushort* __restrict__ A, const ushort* __restrict__ W,
    const float* __restrict__ bias, float* __restrict__ out)
{
    __shared__ ushort As[64][72];
    __shared__ ushort Ws[64][72];

    const int nbase = blockIdx.x * 64;
    const int obase = blockIdx.y * 64;
    const int t    = threadIdx.x;
    const int w    = t >> 6;
    const int lane = t & 63;
    const int l15  = lane & 15;
    const int quad = lane >> 4;
    const int rw   = (w >> 1) * 32;
    const int cw   = (w & 1) * 32;

    f32x4 acc[2][2];
    #pragma unroll
    for (int mt = 0; mt < 2; mt++)
        #pragma unroll
        for (int nt = 0; nt < 2; nt++)
            acc[mt][nt] = (f32x4){0.f, 0.f, 0.f, 0.f};

    for (int kt = 0; kt < DIM / 64; kt++) {
        const int kb = kt * 64;
        __syncthreads();
        #pragma unroll
        for (int i = 0; i < 2; i++) {
            int c = t + i * 256, r = c >> 3, c8 = c & 7;
            *(bf16x8*)&As[r][c8 * 8] =
                *(const bf16x8*)&A[(size_t)(nbase + r) * DIM + kb + c8 * 8];
        }
        #pragma unroll
        for (int i = 0; i < 2; i++) {
            int c = t + i * 256, r = c >> 3, c8 = c & 7;
            *(bf16x8*)&Ws[r][c8 * 8] =
                *(const bf16x8*)&W[(size_t)(obase + r) * DIM + kb + c8 * 8];
        }
        __syncthreads();

        bf16x8 af[2][2], bfr[2][2];
        #pragma unroll
        for (int mt = 0; mt < 2; mt++)
            #pragma unroll
            for (int kh = 0; kh < 2; kh++)
                af[mt][kh] = *(const bf16x8*)&As[rw + mt * 16 + l15][kh * 32 + quad * 8];
        #pragma unroll
        for (int nt = 0; nt < 2; nt++)
            #pragma unroll
            for (int kh = 0; kh < 2; kh++)
                bfr[nt][kh] = *(const bf16x8*)&Ws[cw + nt * 16 + l15][kh * 32 + quad * 8];

        #pragma unroll
        for (int mt = 0; mt < 2; mt++)
            #pragma unroll
            for (int nt = 0; nt < 2; nt++) {
                acc[mt][nt] = __builtin_amdgcn_mfma_f32_16x16x32_bf16(af[mt][0], bfr[nt][0], acc[mt][nt], 0, 0, 0);
                acc[mt][nt] = __builtin_amdgcn_mfma_f32_16x16x32_bf16(af[mt][1], bfr[nt][1], acc[mt][nt], 0, 0, 0);
            }
    }

    #pragma unroll
    for (int nt = 0; nt < 2; nt++) {
        int o = obase + cw + nt * 16 + l15;
        float bb = bias[o];
        #pragma unroll
        for (int mt = 0; mt < 2; mt++) {
            int nrow = nbase + rw + mt * 16 + quad * 4;
            out[(size_t)(nrow + 0) * DIM + o] = acc[mt][nt].x + bb;
            out[(size_t)(nrow + 1) * DIM + o] = acc[mt][nt].y + bb;
            out[(size_t)(nrow + 2) * DIM + o] = acc[mt][nt].z + bb;
            out[(size_t)(nrow + 3) * DIM + o] = acc[mt][nt].w + bb;
        }
    }
}

// ---------------------------------------------------------------------------
extern "C" void kernel_launch(void* const* d_in, const int* in_sizes, int n_in,
                              void* d_out, int out_size, void* d_ws, size_t ws_size,
                              hipStream_t stream)
{
    const float* q        = (const float*)d_in[0];
    const float* k        = (const float*)d_in[1];
    const float* v        = (const float*)d_in[2];
    const float* qk_scale = (const float*)d_in[3];
    const float* w_out    = (const float*)d_in[4];
    const float* b_out    = (const float*)d_in[5];
    float* out = (float*)d_out;

    const size_t per = (size_t)NH * N_CTX * DH;      // 4.19M elements
    ushort* qb    = (ushort*)d_ws;
    ushort* kb    = qb + per;
    ushort* vtg   = kb + per;
    ushort* attnb = vtg + per;                       // (N, DIM) bf16
    ushort* wb    = attnb + per;                     // (DIM, DIM) bf16
    ushort* opart = wb + (size_t)DIM * DIM;          // NSPLIT x (N, DIM) bf16
    float*  lpart = (float*)(opart + (size_t)NSPLIT * N_CTX * DIM);

    prep_kernel<<<dim3(N_CTX * NH / 4, 2), 256, 0, stream>>>(q, k, qk_scale, qb, kb);
    vtrans_kernel<<<dim3(N_CTX / 64, NH), 256, 0, stream>>>(v, vtg);
    wconv_kernel<<<dim3(DIM * DIM / 1024), 256, 0, stream>>>(w_out, wb);
    attn_kernel<<<dim3(N_CTX / 128, NH, NSPLIT), 256, 0, stream>>>(qb, kb, vtg, opart, lpart);
    combine_kernel<<<dim3(N_CTX * DIM / 4 / 256), 256, 0, stream>>>(opart, lpart, attnb);
    proj_kernel<<<dim3(N_CTX / 64, DIM / 64), 256, 0, stream>>>(attnb, wb, b_out, out);
}